// Round 2
// baseline (132.212 us; speedup 1.0000x reference)
//
#include <hip/hip_runtime.h>

// Closed-form: all 10 segment steps are exp(-i*phi_s*H) with the SAME
// traceless Hermitian 2x2 H, so the product is exp(-i*(sum phi)*H).
// infidelity_b = 1 - (cr * sin(DT*S_b*r) / r)^2,  S_b = sum_s omega[b,s]
// loss = mean((infid_data - infidelity)^2)
//
// R7 -> R8: R5/R6/R7 all ~123us total regardless of MLP structure ->
// not latency-bound. Shared trait: per-lane row-chunks (lane stride
// 80-160B) make every float4 wave-load touch 64 distinct 64B lines
// (4x transaction amplification, ~5M vs 1.25M transactions) -> TA-bound
// at ~3.7 TB/s effective. Fix: LDS transpose. Coalesced staging
// (thread k loads f4 k+256j: 16 lines/instr), 44-word padded chunks
// (1 f4 pad per 10 -> aligned conflict-free ds_write_b128), per-thread
// row sums from LDS (rows t+256k -> <=4-way b64 read conflicts, ~free).
// 44KB LDS -> 3 blocks/CU, 123KB/CU reads in flight.

#define ND 2000000
#define BLK 256
#define ROWS_PER_BLOCK 1024                 // 4 rows per thread
#define F4_PER_BLOCK 2560                   // 1024 rows * 10 floats / 4
#define NBLOCKS ((ND + ROWS_PER_BLOCK - 1) / ROWS_PER_BLOCK)   // 1954

__device__ __forceinline__ float sin_small(float th) {
    // |th| <= ~0.062: sin(th) = th*(1 - th^2/6 + th^4/120), err ~ th^7/5040
    const float t2 = th * th;
    return th * (1.0f + t2 * (-(1.0f / 6.0f) + t2 * (1.0f / 120.0f)));
}

__global__ __launch_bounds__(256) void loss_kernel(
    const float* __restrict__ para,
    const float* __restrict__ omega,
    const float* __restrict__ infid,
    float* __restrict__ partial) {

    // 2560 data f4 + 256 pad f4 (one per 10) = 2816 f4 = 11264 words = 44KB
    __shared__ float lds[11264];

    // Scalar precompute (broadcast loads, cached)
    const float x00 = para[0], x01 = para[1], x10 = para[2], x11 = para[3];
    const float a  = 0.5f * (x00 - x11);
    const float cr = 0.5f + 0.5f * (x01 + x10);
    const float ci = 0.5f * (x01 - x10);
    const float r  = sqrtf(a * a + cr * cr + ci * ci);
    const float cr_over_r = cr / r;
    const float dt_r = 0.1f * r;            // DT * r

    const unsigned t = threadIdx.x;
    const unsigned base_row  = (unsigned)blockIdx.x * ROWS_PER_BLOCK;
    const unsigned tile_rows = min((unsigned)ROWS_PER_BLOCK, (unsigned)ND - base_row);
    const unsigned nf4       = (tile_rows * 10u) >> 2;   // tile_rows*2.5, exact

    // ---- Phase 1: coalesced global -> LDS (padded 44-word chunks) ----
    const float4* gof4 = (const float4*)omega + (size_t)blockIdx.x * F4_PER_BLOCK;
    #pragma unroll
    for (int j = 0; j < 10; ++j) {
        const unsigned m = t + 256u * (unsigned)j;       // logical f4 in tile
        if (m < nf4) {
            const float4 v = gof4[m];
            const unsigned pf4 = m + m / 10u;            // chunk pad: +1 f4 per 10
            *(float4*)&lds[4u * pf4] = v;                // 16B-aligned, no straddle
        }
    }
    __syncthreads();

    // ---- Phase 2: per-thread row sums from LDS ----
    float acc = 0.0f;
    #pragma unroll
    for (int k = 0; k < 4; ++k) {
        const unsigned row = t + 256u * (unsigned)k;     // rows t, t+256, ...
        if (row < tile_rows) {
            // row lives in chunk row>>2 (44 words) at word offset (row&3)*10
            const unsigned w = 44u * (row >> 2) + 10u * (row & 3u);  // even -> 8B aligned
            const float2 a0 = *(const float2*)&lds[w + 0];
            const float2 a1 = *(const float2*)&lds[w + 2];
            const float2 a2 = *(const float2*)&lds[w + 4];
            const float2 a3 = *(const float2*)&lds[w + 6];
            const float2 a4 = *(const float2*)&lds[w + 8];
            const float s = (((a0.x + a0.y) + (a1.x + a1.y))
                          +  ((a2.x + a2.y) + (a3.x + a3.y))) + (a4.x + a4.y);

            const float tq = cr_over_r * sin_small(dt_r * s);
            const float d  = infid[base_row + row] - (1.0f - tq * tq);
            acc += d * d;
        }
    }

    // wave (64-lane) shuffle reduction
    #pragma unroll
    for (int off = 32; off > 0; off >>= 1)
        acc += __shfl_down(acc, off, 64);

    __shared__ float wsum[4];               // 256 threads = 4 waves
    const int lane = threadIdx.x & 63;
    const int w    = threadIdx.x >> 6;
    if (lane == 0) wsum[w] = acc;
    __syncthreads();
    if (threadIdx.x == 0) {
        // distinct slot per block: no same-address atomic contention
        partial[blockIdx.x] = (wsum[0] + wsum[1]) + (wsum[2] + wsum[3]);
    }
}

__global__ __launch_bounds__(256) void reduce_kernel(
    const float* __restrict__ partial,
    float* __restrict__ out) {

    const int tid = threadIdx.x;
    float acc = 0.0f;
    #pragma unroll
    for (int i = 0; i < (NBLOCKS + 255) / 256; ++i) {
        const int idx = tid + 256 * i;
        if (idx < NBLOCKS) acc += partial[idx];
    }

    #pragma unroll
    for (int off = 32; off > 0; off >>= 1)
        acc += __shfl_down(acc, off, 64);

    __shared__ float wsum[4];
    const int lane = tid & 63;
    const int w    = tid >> 6;
    if (lane == 0) wsum[w] = acc;
    __syncthreads();
    if (tid == 0)
        out[0] = ((wsum[0] + wsum[1]) + (wsum[2] + wsum[3])) * (1.0f / (float)ND);
}

extern "C" void kernel_launch(void* const* d_in, const int* in_sizes, int n_in,
                              void* d_out, int out_size, void* d_ws, size_t ws_size,
                              hipStream_t stream) {
    const float* para  = (const float*)d_in[0];   // (2,2)
    const float* omega = (const float*)d_in[1];   // (2M, 10)
    const float* infid = (const float*)d_in[2];   // (2M,)
    float* out     = (float*)d_out;
    float* partial = (float*)d_ws;                // NBLOCKS * 4 B

    loss_kernel<<<NBLOCKS, BLK, 0, stream>>>(para, omega, infid, partial);
    reduce_kernel<<<1, 256, 0, stream>>>(partial, out);
}

// Round 3
// 123.605 us; speedup vs baseline: 1.0696x; 1.0696x over previous
//
#include <hip/hip_runtime.h>

// Closed-form: all 10 segment steps are exp(-i*phi_s*H) with the SAME
// traceless Hermitian 2x2 H, so the product is exp(-i*(sum phi)*H).
// infidelity_b = 1 - (cr * sin(DT*S_b*r) / r)^2,  S_b = sum_s omega[b,s]
// loss = mean((infid_data - infidelity)^2)
//
// R8 -> R9: R8's reg-staged LDS transpose regressed (+8us): wave
// ds_write_b128 has only 8 bank-groups -> >=8-way serialization, plus
// the VGPR round trip. Clean coalescing test: global_load_lds staging
// (HW writes LDS linearly, base + lane*16; no ds_write, no VGPR trip).
// Staging = 16 lines/instr fill-like pattern (vs R7's 64 lines/instr).
// Linear [row][10] LDS, phase-2 b64 reads at stride 10 words = 4-way =
// the b64 wave floor (512B/128B-per-clk), no padding needed. 40KB LDS
// -> 4 blocks/CU. Tail tile = 128 rows = exactly 5 chunks (guard stays
// wave-uniform). Pre-commit: total >= 121us refutes coalescing theory
// -> revert + roofline.

#define ND 2000000
#define BLK 256
#define ROWS_PER_BLOCK 1024
#define TILE_BYTES (ROWS_PER_BLOCK * 40)                       // 40960
#define NCHUNK (TILE_BYTES / 1024)                             // 40 (10/wave)
#define NBLOCKS ((ND + ROWS_PER_BLOCK - 1) / ROWS_PER_BLOCK)   // 1954

typedef __attribute__((address_space(1))) const void gvoid_t;
typedef __attribute__((address_space(3))) void lvoid_t;

__device__ __forceinline__ float sin_small(float th) {
    // |th| <= ~0.062: sin(th) = th*(1 - th^2/6 + th^4/120), err ~ th^7/5040
    const float t2 = th * th;
    return th * (1.0f + t2 * (-(1.0f / 6.0f) + t2 * (1.0f / 120.0f)));
}

__global__ __launch_bounds__(256) void loss_kernel(
    const float* __restrict__ para,
    const float* __restrict__ omega,
    const float* __restrict__ infid,
    float* __restrict__ partial) {

    __shared__ float lds[TILE_BYTES / 4];   // 10240 floats, LINEAR layout

    // Scalar precompute (broadcast loads, cached)
    const float x00 = para[0], x01 = para[1], x10 = para[2], x11 = para[3];
    const float a  = 0.5f * (x00 - x11);
    const float cr = 0.5f + 0.5f * (x01 + x10);
    const float ci = 0.5f * (x01 - x10);
    const float r  = sqrtf(a * a + cr * cr + ci * ci);
    const float cr_over_r = cr / r;
    const float dt_r = 0.1f * r;            // DT * r

    const unsigned t    = threadIdx.x;
    const unsigned lane = t & 63u;
    const unsigned wave = t >> 6;
    const unsigned base_row  = (unsigned)blockIdx.x * ROWS_PER_BLOCK;
    const unsigned tile_rows = min((unsigned)ROWS_PER_BLOCK, (unsigned)ND - base_row);
    const unsigned tile_bytes = tile_rows * 40u;

    // ---- Phase 1: async global -> LDS, fully coalesced (1KB/instr) ----
    const char* gtile = (const char*)omega + (size_t)base_row * 40u;
    #pragma unroll
    for (int j = 0; j < NCHUNK / 4; ++j) {
        const unsigned c  = wave * (NCHUNK / 4) + (unsigned)j;  // chunk 0..39
        const unsigned cb = c * 1024u;
        if (cb + 1024u <= tile_bytes) {      // wave-uniform (tail = exact chunks)
            __builtin_amdgcn_global_load_lds(
                (gvoid_t*)(gtile + cb + lane * 16u),   // per-lane global src
                (lvoid_t*)((char*)lds + cb),           // wave-uniform LDS base
                16, 0, 0);
        }
    }

    // prefetch infid into regs; completes during the vmcnt(0) drain below
    float fi[4];
    #pragma unroll
    for (int k = 0; k < 4; ++k) {
        const unsigned row = t + 256u * (unsigned)k;
        fi[k] = (row < tile_rows) ? infid[base_row + row] : 0.0f;
    }

    asm volatile("s_waitcnt vmcnt(0)" ::: "memory");
    __syncthreads();

    // ---- Phase 2: per-thread row sums from LDS (b64, at wave floor) ----
    float acc = 0.0f;
    #pragma unroll
    for (int k = 0; k < 4; ++k) {
        const unsigned row = t + 256u * (unsigned)k;
        if (row < tile_rows) {
            const unsigned w = row * 10u;                 // even -> 8B aligned
            const float2 a0 = *(const float2*)&lds[w + 0];
            const float2 a1 = *(const float2*)&lds[w + 2];
            const float2 a2 = *(const float2*)&lds[w + 4];
            const float2 a3 = *(const float2*)&lds[w + 6];
            const float2 a4 = *(const float2*)&lds[w + 8];
            const float s = (((a0.x + a0.y) + (a1.x + a1.y))
                          +  ((a2.x + a2.y) + (a3.x + a3.y))) + (a4.x + a4.y);

            const float tq = cr_over_r * sin_small(dt_r * s);
            const float d  = fi[k] - (1.0f - tq * tq);
            acc += d * d;
        }
    }

    // wave (64-lane) shuffle reduction
    #pragma unroll
    for (int off = 32; off > 0; off >>= 1)
        acc += __shfl_down(acc, off, 64);

    __shared__ float wsum[4];               // 256 threads = 4 waves
    const int w    = threadIdx.x >> 6;
    if (lane == 0) wsum[w] = acc;
    __syncthreads();
    if (threadIdx.x == 0) {
        // distinct slot per block: no same-address atomic contention
        partial[blockIdx.x] = (wsum[0] + wsum[1]) + (wsum[2] + wsum[3]);
    }
}

__global__ __launch_bounds__(256) void reduce_kernel(
    const float* __restrict__ partial,
    float* __restrict__ out) {

    const int tid = threadIdx.x;
    float acc = 0.0f;
    #pragma unroll
    for (int i = 0; i < (NBLOCKS + 255) / 256; ++i) {
        const int idx = tid + 256 * i;
        if (idx < NBLOCKS) acc += partial[idx];
    }

    #pragma unroll
    for (int off = 32; off > 0; off >>= 1)
        acc += __shfl_down(acc, off, 64);

    __shared__ float wsum[4];
    const int lane = tid & 63;
    const int w    = tid >> 6;
    if (lane == 0) wsum[w] = acc;
    __syncthreads();
    if (tid == 0)
        out[0] = ((wsum[0] + wsum[1]) + (wsum[2] + wsum[3])) * (1.0f / (float)ND);
}

extern "C" void kernel_launch(void* const* d_in, const int* in_sizes, int n_in,
                              void* d_out, int out_size, void* d_ws, size_t ws_size,
                              hipStream_t stream) {
    const float* para  = (const float*)d_in[0];   // (2,2)
    const float* omega = (const float*)d_in[1];   // (2M, 10)
    const float* infid = (const float*)d_in[2];   // (2M,)
    float* out     = (float*)d_out;
    float* partial = (float*)d_ws;                // NBLOCKS * 4 B

    loss_kernel<<<NBLOCKS, BLK, 0, stream>>>(para, omega, infid, partial);
    reduce_kernel<<<1, 256, 0, stream>>>(partial, out);
}